// Round 17
// baseline (297.107 us; speedup 1.0000x reference)
//
#include <hip/hip_runtime.h>

typedef unsigned short u16;
typedef unsigned int u32;
typedef __bf16 bf16x4 __attribute__((ext_vector_type(4)));
typedef __bf16 bf16x8 __attribute__((ext_vector_type(8)));
typedef float f32x4 __attribute__((ext_vector_type(4)));
typedef float f32x16 __attribute__((ext_vector_type(16)));

#define BATCH 4
#define SLEN 2048
#define DMODEL 1024
#define NHEAD 16
#define DHEAD 64
#define MROWS (BATCH * SLEN) /* 8192 */

__device__ __forceinline__ u16 f32_to_bf16(float f) {
  u32 u = __float_as_uint(f);
  u32 r = (u + 0x7FFFu + ((u >> 16) & 1u)) >> 16;
  return (u16)r;
}
__device__ __forceinline__ u32 pack_bf16x2(float a, float b) {
  return (u32)f32_to_bf16(a) | ((u32)f32_to_bf16(b) << 16);
}

// pack two f32 -> two bf16 (truncate), 1 v_perm_b32
__device__ __forceinline__ u32 pack_trunc(float lo, float hi) {
#if __has_builtin(__builtin_amdgcn_perm)
  return __builtin_amdgcn_perm(__float_as_uint(hi), __float_as_uint(lo), 0x07060302u);
#else
  return (__float_as_uint(hi) & 0xFFFF0000u) | (__float_as_uint(lo) >> 16);
#endif
}
// pack with round-half-up (epilogue)
__device__ __forceinline__ u32 pack_round(float lo, float hi) {
  u32 ul = __float_as_uint(lo) + 0x8000u;
  u32 uh = __float_as_uint(hi) + 0x8000u;
#if __has_builtin(__builtin_amdgcn_perm)
  return __builtin_amdgcn_perm(uh, ul, 0x07060302u);
#else
  return (uh & 0xFFFF0000u) | (ul >> 16);
#endif
}

#if __has_builtin(__builtin_amdgcn_exp2f)
#define EXP2(x) __builtin_amdgcn_exp2f(x)
#else
#define EXP2(x) exp2f(x)
#endif

// async global->LDS, 16 B per lane; lds dest = wave-uniform base + lane*16
typedef const __attribute__((address_space(1))) void* gas_cv;
typedef __attribute__((address_space(3))) void* las_v;
__device__ __forceinline__ void async16(const u16* g, u16* l) {
  __builtin_amdgcn_global_load_lds((gas_cv)g, (las_v)l, 16, 0, 0);
}

// ---------------- fused prep kernel (R16 win, unchanged) ----------------
__global__ void prep_kernel(const float* __restrict__ x, const float* __restrict__ Wq,
                            const float* __restrict__ Wk, const float* __restrict__ Wv,
                            const float* __restrict__ Wo, const float* __restrict__ bq,
                            const float* __restrict__ bk, const float* __restrict__ bv,
                            u16* __restrict__ xb, u16* __restrict__ wqkvt,
                            u16* __restrict__ wot, float* __restrict__ bqkv) {
  const int bid = blockIdx.x;
  if (bid < 4096) {
    size_t i = ((size_t)bid * 256 + threadIdx.x) * 8;
    float4 v0 = *(const float4*)(x + i);
    float4 v1 = *(const float4*)(x + i + 4);
    uint4 o;
    o.x = pack_bf16x2(v0.x, v0.y);
    o.y = pack_bf16x2(v0.z, v0.w);
    o.z = pack_bf16x2(v1.x, v1.y);
    o.w = pack_bf16x2(v1.z, v1.w);
    *(uint4*)(xb + i) = o;
  } else if (bid < 8192) {
    __shared__ float tile[32][33];
    const int idx = bid - 4096;
    const int z = idx >> 10;
    const int rem = idx & 1023;
    const float* src = (z == 0) ? Wq : (z == 1) ? Wk : (z == 2) ? Wv : Wo;
    u16* dst = (z < 3) ? (wqkvt + (size_t)z * DMODEL * DMODEL) : wot;
    const int c0 = (rem & 31) * 32, r0 = (rem >> 5) * 32;
    const int tx = threadIdx.x & 31, ty = threadIdx.x >> 5;
#pragma unroll
    for (int i = 0; i < 4; ++i)
      tile[ty + 8 * i][tx] = src[(size_t)(r0 + ty + 8 * i) * DMODEL + c0 + tx];
    __syncthreads();
#pragma unroll
    for (int i = 0; i < 4; ++i)
      dst[(size_t)(c0 + ty + 8 * i) * DMODEL + r0 + tx] = f32_to_bf16(tile[tx][ty + 8 * i]);
  } else {
    const int i = (bid - 8192) * 256 + threadIdx.x;
    float v = (i < 1024) ? bq[i] : (i < 2048) ? bk[i - 1024] : bv[i - 2048];
    bqkv[i] = v;
  }
}

// ---------------- GEMM v4 (QKV): 256x128 tile, 2x2 waves of 128x64 ----------------
// R16 diagnosis: inner loop is LDS-read-port bound (32KB reads per 128^2 block-iter =
// 384 port-cyc vs 80 MFMA-cyc; x2.3 blocks/CU = the 915cyc/iter wall; conflicts 0).
// Fix: bigger tile -> fewer bytes/FLOP. 256x128 block (2x2 waves of 128x64): reads =
// 48KB per 2 MFLOP = 0.75x port time per FLOP. LDS 48KB dbuf, ~200 VGPR (no
// launch_bounds 2nd arg - the v17 64-cap lesson). Sync/swizzle skeleton byte-identical
// to the validated v3 (counted vmcnt(6), 2 raw barriers; (row>>1)&3 swizzle is
// invariant under +64-row shifts so both sides carry over).
__global__ __launch_bounds__(256) void gemm256_bt_kernel(const u16* __restrict__ A,
                                                         const u16* __restrict__ Bt,
                                                         const float* __restrict__ bias,
                                                         u16* __restrict__ Cout,
                                                         u16* __restrict__ vtout,
                                                         int M, int N, int K) {
  __shared__ u16 sA[2][256 * 32];
  __shared__ u16 sB[2][128 * 32];
  const int tid = threadIdx.x;
  const int wv = tid >> 6, lane = tid & 63;
  const int wr = wv >> 1, wc = wv & 1;
  const int col = lane & 15, quad = lane >> 4;
  const int m0 = blockIdx.x * 256;
  const int n0 = blockIdx.y * 128;

  f32x4 acc[8][4] = {};

  const int lr = tid >> 2;
  const int ls = (tid & 3) ^ ((lr >> 1) & 3); // swizzled global 16B-seg (stage side)
  const size_t a_base = (size_t)(m0 + lr) * K + ls * 8;
  const size_t b_base = (size_t)(n0 + lr) * K + ls * 8;
  const int wvo = (tid >> 6) << 9; // per-wave 1KB chunk (u16 units) within a 64-row round
  const int sseg = ((col >> 1) & 3);

  // prologue: stage K-tile 0 into buffer 0 (A 4 rounds of 64 rows, B 2 rounds)
#pragma unroll
  for (int r = 0; r < 4; ++r)
    async16(A + a_base + (size_t)(r * 64) * K, sA[0] + r * 2048 + wvo);
#pragma unroll
  for (int r = 0; r < 2; ++r)
    async16(Bt + b_base + (size_t)(r * 64) * K, sB[0] + r * 2048 + wvo);

  const int nit = K >> 5;
  for (int it = 0; it < nit; ++it) {
    const int cur = it & 1, nxt = cur ^ 1;

    if (it + 1 < nit) {
      const int k0 = (it + 1) << 5;
#pragma unroll
      for (int r = 0; r < 4; ++r)
        async16(A + a_base + (size_t)(r * 64) * K + k0, sA[nxt] + r * 2048 + wvo);
#pragma unroll
      for (int r = 0; r < 2; ++r)
        async16(Bt + b_base + (size_t)(r * 64) * K + k0, sB[nxt] + r * 2048 + wvo);
      asm volatile("s_waitcnt vmcnt(6)");
    } else {
      asm volatile("s_waitcnt vmcnt(0)");
    }
    __builtin_amdgcn_sched_barrier(0);
    __builtin_amdgcn_s_barrier(); // B1: K-tile it staged by ALL waves
    __builtin_amdgcn_sched_barrier(0);

    const int rseg = (quad ^ sseg) * 8;
    bf16x8 af[8], bfr[4];
#pragma unroll
    for (int i = 0; i < 8; ++i)
      af[i] = *(const bf16x8*)(sA[cur] + (wr * 128 + i * 16 + col) * 32 + rseg);
#pragma unroll
    for (int j = 0; j < 4; ++j)
      bfr[j] = *(const bf16x8*)(sB[cur] + (wc * 64 + j * 16 + col) * 32 + rseg);
#pragma unroll
    for (int i = 0; i < 8; ++i)
#pragma unroll
      for (int j = 0; j < 4; ++j)
        acc[i][j] = __builtin_amdgcn_mfma_f32_16x16x32_bf16(af[i], bfr[j], acc[i][j], 0, 0, 0);

    __builtin_amdgcn_sched_barrier(0);
    __builtin_amdgcn_s_barrier(); // B2: all waves done reading cur (no vmcnt drain)
    __builtin_amdgcn_sched_barrier(0);
  }

  // epilogue: Q|K columns -> qk (stride 2048); V columns (n>=2048) -> vt fused
#pragma unroll
  for (int i = 0; i < 8; ++i) {
#pragma unroll
    for (int j = 0; j < 4; ++j) {
      int n = n0 + wc * 64 + j * 16 + col;
      float bia = bias[n];
      if (n >= 2 * DMODEL) {
        const int hh = (n - 2 * DMODEL) >> 6, dh = n & 63;
        const int mb = m0 + wr * 128 + i * 16 + quad * 4;
        const int bb = mb >> 11, s0 = mb & 2047;
        uint2 pk;
        pk.x = pack_bf16x2(acc[i][j][0] + bia, acc[i][j][1] + bia);
        pk.y = pack_bf16x2(acc[i][j][2] + bia, acc[i][j][3] + bia);
        *(uint2*)(vtout + ((size_t)((bb * 16 + hh) * 64 + dh)) * SLEN + s0) = pk;
      } else {
#pragma unroll
        for (int r = 0; r < 4; ++r) {
          int m = m0 + wr * 128 + i * 16 + quad * 4 + r;
          Cout[(size_t)m * (2 * DMODEL) + n] = f32_to_bf16(acc[i][j][r] + bia);
        }
      }
    }
  }
}

// ---------------- GEMM v3 (out-proj): 128x128, dbuf + counted-vmcnt + swizzle (R15) ----------------
__global__ __launch_bounds__(256) void gemm_bt_kernel(const u16* __restrict__ A,
                                                      const u16* __restrict__ Bt,
                                                      const float* __restrict__ bias,
                                                      float* __restrict__ Cout,
                                                      int M, int N, int K) {
  __shared__ u16 sA[2][128 * 32];
  __shared__ u16 sB[2][128 * 32];
  const int tid = threadIdx.x;
  const int wv = tid >> 6, lane = tid & 63;
  const int wr = wv >> 1, wc = wv & 1;
  const int col = lane & 15, quad = lane >> 4;
  const int m0 = blockIdx.x * 128;
  const int n0 = blockIdx.y * 128;

  f32x4 acc[4][4] = {};

  const int lr = tid >> 2;
  const int ls = (tid & 3) ^ ((lr >> 1) & 3);
  const size_t a_base = (size_t)(m0 + lr) * K + ls * 8;
  const size_t b_base = (size_t)(n0 + lr) * K + ls * 8;
  const int wvo = (tid >> 6) << 9;
  const int sseg = ((col >> 1) & 3);

  async16(A + a_base, sA[0] + wvo);
  async16(A + a_base + (size_t)64 * K, sA[0] + wvo + 2048);
  async16(Bt + b_base, sB[0] + wvo);
  async16(Bt + b_base + (size_t)64 * K, sB[0] + wvo + 2048);

  const int nit = K >> 5;
  for (int it = 0; it < nit; ++it) {
    const int cur = it & 1, nxt = cur ^ 1;

    if (it + 1 < nit) {
      const int k0 = (it + 1) << 5;
      async16(A + a_base + k0, sA[nxt] + wvo);
      async16(A + a_base + (size_t)64 * K + k0, sA[nxt] + wvo + 2048);
      async16(Bt + b_base + k0, sB[nxt] + wvo);
      async16(Bt + b_base + (size_t)64 * K + k0, sB[nxt] + wvo + 2048);
      asm volatile("s_waitcnt vmcnt(4)");
    } else {
      asm volatile("s_waitcnt vmcnt(0)");
    }
    __builtin_amdgcn_sched_barrier(0);
    __builtin_amdgcn_s_barrier();
    __builtin_amdgcn_sched_barrier(0);

    const int rseg = (quad ^ sseg) * 8;
    bf16x8 af[4], bfr[4];
#pragma unroll
    for (int i = 0; i < 4; ++i)
      af[i] = *(const bf16x8*)(sA[cur] + (wr * 64 + i * 16 + col) * 32 + rseg);
#pragma unroll
    for (int j = 0; j < 4; ++j)
      bfr[j] = *(const bf16x8*)(sB[cur] + (wc * 64 + j * 16 + col) * 32 + rseg);
#pragma unroll
    for (int i = 0; i < 4; ++i)
#pragma unroll
      for (int j = 0; j < 4; ++j)
        acc[i][j] = __builtin_amdgcn_mfma_f32_16x16x32_bf16(af[i], bfr[j], acc[i][j], 0, 0, 0);

    __builtin_amdgcn_sched_barrier(0);
    __builtin_amdgcn_s_barrier();
    __builtin_amdgcn_sched_barrier(0);
  }

#pragma unroll
  for (int i = 0; i < 4; ++i) {
#pragma unroll
    for (int j = 0; j < 4; ++j) {
      int n = n0 + wc * 64 + j * 16 + col;
      float bia = bias[n];
#pragma unroll
      for (int r = 0; r < 4; ++r) {
        int m = m0 + wr * 64 + i * 16 + quad * 4 + r;
        Cout[(size_t)m * N + n] = acc[i][j][r] + bia;
      }
    }
  }
}

// ---------------- flash attention v18: grid (16,64), no register cap (R14 best, unchanged) ----------------
__global__ __launch_bounds__(256, 2) void attn_kernel(const u16* __restrict__ qk,
                                                      const u16* __restrict__ vt,
                                                      u16* __restrict__ out) {
  const int lid = blockIdx.y * 16 + blockIdx.x; // [0,1024)
  const int xcd = lid & 7;
  const int local = lid >> 3;            // [0,128)
  const int bh = xcd * 8 + (local & 7);  // same-bh blocks share XCD
  const int bx = 15 - (local >> 3);      // 0..15, heavy blocks (large bx) launch early
  const int b = bh >> 4, h = bh & 15;
  const int tid = threadIdx.x;
  const int wv = tid >> 6, lane = tid & 63;
  const int c = lane & 31, hi = lane >> 5;
  const int s = bx * 4 + wv; // strip id 0..63 (32 q-rows each)

  __shared__ u16 sK[2][64 * 64];
  __shared__ u16 sV[2][64 * 64];

  const u16* kbase = qk + ((size_t)(b * SLEN)) * (2 * DMODEL) + DMODEL + h * DHEAD;
  const u16* vbase = vt + ((size_t)bh * DHEAD) * SLEN;
  const float scl2 = 0.125f * 1.44269504088896f; // 1/sqrt(dh) * log2(e)

  const int lrow = lane >> 3;
  const int sga = (lane & 7) ^ lrow;
  const int r0a = wv * 16, r0b = wv * 16 + 8;
  const int cs = c & 7;

  const int qbase = s * 32;
  const int nt_own = s / 2 + 1;
  const int nt = 2 * bx + 2; // block-uniform staging sweep (= max nt_own in block)

  const u16* qrow =
      qk + ((size_t)(b * SLEN + qbase + c)) * (2 * DMODEL) + h * DHEAD + hi * 8;
  bf16x8 aQ[4];
#pragma unroll
  for (int ks = 0; ks < 4; ++ks) aQ[ks] = *(const bf16x8*)(qrow + ks * 16);

  f32x16 accO[2] = {}; // [mdh]: O^T, col=q=c, row=dh=mdh*32+(r&3)+8*(r>>2)+4*hi
  float m2 = -1e30f, l_i = 0.0f;

  async16(kbase + (size_t)(r0a + lrow) * (2 * DMODEL) + sga * 8, sK[0] + r0a * 64);
  async16(kbase + (size_t)(r0b + lrow) * (2 * DMODEL) + sga * 8, sK[0] + r0b * 64);
  async16(vbase + (size_t)(r0a + lrow) * SLEN + sga * 8, sV[0] + r0a * 64);
  async16(vbase + (size_t)(r0b + lrow) * SLEN + sga * 8, sV[0] + r0b * 64);

  for (int t = 0; t < nt; ++t) {
    const int kv0 = t * 64;
    const int cur = t & 1, nxt = cur ^ 1;

    if (t + 1 < nt) {
      const int kvn = kv0 + 64;
      async16(kbase + (size_t)(kvn + r0a + lrow) * (2 * DMODEL) + sga * 8, sK[nxt] + r0a * 64);
      async16(kbase + (size_t)(kvn + r0b + lrow) * (2 * DMODEL) + sga * 8, sK[nxt] + r0b * 64);
      async16(vbase + (size_t)(r0a + lrow) * SLEN + kvn + sga * 8, sV[nxt] + r0a * 64);
      async16(vbase + (size_t)(r0b + lrow) * SLEN + kvn + sga * 8, sV[nxt] + r0b * 64);
      asm volatile("s_waitcnt vmcnt(4)");
    } else {
      asm volatile("s_waitcnt vmcnt(0)");
    }
    __builtin_amdgcn_sched_barrier(0);
    __builtin_amdgcn_s_barrier(); // B1: tile t staged by ALL waves
    __builtin_amdgcn_sched_barrier(0);

    if (t < nt_own) {
      const u16* sKc = sK[cur];
      const u16* sVc = sV[cur];
      bf16x8 bK[2][4], bV[2][4];
#pragma unroll
      for (int m = 0; m < 2; ++m) {
        const int rb = (m * 32 + c) * 64;
#pragma unroll
        for (int ks = 0; ks < 4; ++ks) {
          bK[m][ks] = *(const bf16x8*)(sKc + rb + (((ks * 2 + hi) ^ cs) << 3));
          bf16x4 vlo = *(const bf16x4*)(sVc + rb + (((ks * 2) ^ cs) << 3) + 4 * hi);
          bf16x4 vhi = *(const bf16x4*)(sVc + rb + (((ks * 2 + 1) ^ cs) << 3) + 4 * hi);
          bV[m][ks] = __builtin_shufflevector(vlo, vhi, 0, 1, 2, 3, 4, 5, 6, 7);
        }
      }

      f32x16 accST[2] = {};
      __builtin_amdgcn_s_setprio(1);
#pragma unroll
      for (int ks = 0; ks < 4; ++ks)
#pragma unroll
        for (int m = 0; m < 2; ++m)
          accST[m] = __builtin_amdgcn_mfma_f32_32x32x16_bf16(bK[m][ks], aQ[ks],
                                                             accST[m], 0, 0, 0);
      __builtin_amdgcn_s_setprio(0);

      if (t == nt_own - 1) {
        const int q = qbase + c;
        const int kvh = kv0 + 4 * hi;
#pragma unroll
        for (int m = 0; m < 2; ++m)
#pragma unroll
          for (int r = 0; r < 16; ++r) {
            int kv = kvh + m * 32 + ((r & 3) + 8 * (r >> 2));
            if (kv > q) accST[m][r] = -1e30f;
          }
      }

      float h0 = fmaxf(fmaxf(accST[0][0], accST[0][1]), fmaxf(accST[0][2], accST[0][3]));
      float h1 = fmaxf(fmaxf(accST[0][4], accST[0][5]), fmaxf(accST[0][6], accST[0][7]));
      float h2 = fmaxf(fmaxf(accST[0][8], accST[0][9]), fmaxf(accST[0][10], accST[0][11]));
      float h3 = fmaxf(fmaxf(accST[0][12], accST[0][13]), fmaxf(accST[0][14], accST[0][15]));
      float h4 = fmaxf(fmaxf(accST[1][0], accST[1][1]), fmaxf(accST[1][2], accST[1][3]));
      float h5 = fmaxf(fmaxf(accST[1][4], accST[1][5]), fmaxf(accST[1][6], accST[1][7]));
      float h6 = fmaxf(fmaxf(accST[1][8], accST[1][9]), fmaxf(accST[1][10], accST[1][11]));
      float h7 = fmaxf(fmaxf(accST[1][12], accST[1][13]), fmaxf(accST[1][14], accST[1][15]));
      float rmax = fmaxf(fmaxf(fmaxf(h0, h1), fmaxf(h2, h3)),
                         fmaxf(fmaxf(h4, h5), fmaxf(h6, h7)));
      rmax = fmaxf(rmax, __shfl_xor(rmax, 32));
      float rmaxs = rmax * scl2;
      const bool noresc = __all(rmaxs <= m2);
      float mnew = noresc ? m2 : fmaxf(m2, rmaxs);
      float alpha = noresc ? 1.0f : EXP2(m2 - mnew);
      m2 = mnew;

      float s0 = 0.f, s1 = 0.f, s2s = 0.f, s3 = 0.f;
#pragma unroll
      for (int m = 0; m < 2; ++m) {
#pragma unroll
        for (int r = 0; r < 16; r += 4) {
          float p0 = EXP2(__builtin_fmaf(accST[m][r + 0], scl2, -mnew));
          float p1 = EXP2(__builtin_fmaf(accST[m][r + 1], scl2, -mnew));
          float p2 = EXP2(__builtin_fmaf(accST[m][r + 2], scl2, -mnew));
          float p3 = EXP2(__builtin_fmaf(accST[m][r + 3], scl2, -mnew));
          accST[m][r + 0] = p0;
          accST[m][r + 1] = p1;
          accST[m][r + 2] = p2;
          accST[m][r + 3] = p3;
          s0 += p0;
          s1 += p1;
          s2s += p2;
          s3 += p3;
        }
      }
      float sacc = (s0 + s1) + (s2s + s3);
      sacc += __shfl_xor(sacc, 32);
      if (noresc) {
        l_i += sacc;
      } else {
        l_i = l_i * alpha + sacc;
#pragma unroll
        for (int m = 0; m < 2; ++m)
#pragma unroll
          for (int r = 0; r < 16; ++r) accO[m][r] *= alpha;
      }

      bf16x8 aP[4];
#pragma unroll
      for (int m = 0; m < 2; ++m)
#pragma unroll
        for (int sp = 0; sp < 2; ++sp) {
          union {
            uint4 u;
            bf16x8 v;
          } cvt;
          cvt.u.x = pack_trunc(accST[m][8 * sp + 0], accST[m][8 * sp + 1]);
          cvt.u.y = pack_trunc(accST[m][8 * sp + 2], accST[m][8 * sp + 3]);
          cvt.u.z = pack_trunc(accST[m][8 * sp + 4], accST[m][8 * sp + 5]);
          cvt.u.w = pack_trunc(accST[m][8 * sp + 6], accST[m][8 * sp + 7]);
          aP[m * 2 + sp] = cvt.v;
        }

      __builtin_amdgcn_s_setprio(1);
#pragma unroll
      for (int ks = 0; ks < 4; ++ks)
#pragma unroll
        for (int m = 0; m < 2; ++m)
          accO[m] = __builtin_amdgcn_mfma_f32_32x32x16_bf16(bV[m][ks], aP[ks],
                                                            accO[m], 0, 0, 0);
      __builtin_amdgcn_s_setprio(0);
    }

    __builtin_amdgcn_sched_barrier(0);
    __builtin_amdgcn_s_barrier(); // B2: all waves done reading cur (no vmcnt drain)
    __builtin_amdgcn_sched_barrier(0);
  }

  {
    float rl = 1.0f / l_i;
    size_t rowoff =
        ((size_t)(b * SLEN + qbase + c)) * DMODEL + h * DHEAD + 4 * hi;
#pragma unroll
    for (int m = 0; m < 2; ++m)
#pragma unroll
      for (int j = 0; j < 4; ++j) {
        uint2 pk;
        pk.x = pack_round(accO[m][4 * j + 0] * rl, accO[m][4 * j + 1] * rl);
        pk.y = pack_round(accO[m][4 * j + 2] * rl, accO[m][4 * j + 3] * rl);
        *(uint2*)(out + rowoff + m * 32 + 8 * j) = pk;
      }
  }
}

// ---------------- launch ----------------

extern "C" void kernel_launch(void* const* d_in, const int* in_sizes, int n_in,
                              void* d_out, int out_size, void* d_ws, size_t ws_size,
                              hipStream_t stream) {
  const float* x = (const float*)d_in[0];
  const float* Wq = (const float*)d_in[1];
  const float* bq = (const float*)d_in[2];
  const float* Wk = (const float*)d_in[3];
  const float* bk = (const float*)d_in[4];
  const float* Wv = (const float*)d_in[5];
  const float* bv = (const float*)d_in[6];
  const float* Wo = (const float*)d_in[7];
  const float* bo = (const float*)d_in[8];

  char* ws = (char*)d_ws;
  u16* xb = (u16*)ws;                              // 16 MB
  u16* wqkvt = (u16*)(ws + ((size_t)16 << 20));    // 6 MB
  u16* wot = (u16*)(ws + ((size_t)22 << 20));      // 2 MB
  u16* qk = (u16*)(ws + ((size_t)24 << 20));       // 32 MB (Q|K, row stride 2048)
  u16* vtp = (u16*)(ws + ((size_t)56 << 20));      // 16 MB (V transposed, fused write)
  u16* attnO = (u16*)(ws + ((size_t)72 << 20));    // 16 MB
  float* bqkv = (float*)(ws + ((size_t)88 << 20)); // 12 KB

  prep_kernel<<<8204, 256, 0, stream>>>(x, Wq, Wk, Wv, Wo, bq, bk, bv,
                                        xb, wqkvt, wot, bqkv);
  gemm256_bt_kernel<<<dim3(32, 24), 256, 0, stream>>>(xb, wqkvt, bqkv, qk, vtp,
                                                      MROWS, 3 * DMODEL, DMODEL);
  attn_kernel<<<dim3(16, 64), 256, 0, stream>>>(qk, vtp, attnO);
  gemm_bt_kernel<<<dim3(64, 8), 256, 0, stream>>>(attnO, wot, bo, (float*)d_out,
                                                  MROWS, DMODEL, DMODEL);
}

// Round 18
// 254.253 us; speedup vs baseline: 1.1686x; 1.1686x over previous
//
#include <hip/hip_runtime.h>

typedef unsigned short u16;
typedef unsigned int u32;
typedef __bf16 bf16x4 __attribute__((ext_vector_type(4)));
typedef __bf16 bf16x8 __attribute__((ext_vector_type(8)));
typedef float f32x4 __attribute__((ext_vector_type(4)));
typedef float f32x16 __attribute__((ext_vector_type(16)));

#define BATCH 4
#define SLEN 2048
#define DMODEL 1024
#define NHEAD 16
#define DHEAD 64
#define MROWS (BATCH * SLEN) /* 8192 */

__device__ __forceinline__ u16 f32_to_bf16(float f) {
  u32 u = __float_as_uint(f);
  u32 r = (u + 0x7FFFu + ((u >> 16) & 1u)) >> 16;
  return (u16)r;
}
__device__ __forceinline__ u32 pack_bf16x2(float a, float b) {
  return (u32)f32_to_bf16(a) | ((u32)f32_to_bf16(b) << 16);
}

// pack two f32 -> two bf16 (truncate), 1 v_perm_b32
__device__ __forceinline__ u32 pack_trunc(float lo, float hi) {
#if __has_builtin(__builtin_amdgcn_perm)
  return __builtin_amdgcn_perm(__float_as_uint(hi), __float_as_uint(lo), 0x07060302u);
#else
  return (__float_as_uint(hi) & 0xFFFF0000u) | (__float_as_uint(lo) >> 16);
#endif
}
// pack with round-half-up (epilogue)
__device__ __forceinline__ u32 pack_round(float lo, float hi) {
  u32 ul = __float_as_uint(lo) + 0x8000u;
  u32 uh = __float_as_uint(hi) + 0x8000u;
#if __has_builtin(__builtin_amdgcn_perm)
  return __builtin_amdgcn_perm(uh, ul, 0x07060302u);
#else
  return (uh & 0xFFFF0000u) | (ul >> 16);
#endif
}

#if __has_builtin(__builtin_amdgcn_exp2f)
#define EXP2(x) __builtin_amdgcn_exp2f(x)
#else
#define EXP2(x) exp2f(x)
#endif

// async global->LDS, 16 B per lane; lds dest = wave-uniform base + lane*16
typedef const __attribute__((address_space(1))) void* gas_cv;
typedef __attribute__((address_space(3))) void* las_v;
__device__ __forceinline__ void async16(const u16* g, u16* l) {
  __builtin_amdgcn_global_load_lds((gas_cv)g, (las_v)l, 16, 0, 0);
}

// ---------------- fused prep kernel (R16 win, unchanged) ----------------
__global__ void prep_kernel(const float* __restrict__ x, const float* __restrict__ Wq,
                            const float* __restrict__ Wk, const float* __restrict__ Wv,
                            const float* __restrict__ Wo, const float* __restrict__ bq,
                            const float* __restrict__ bk, const float* __restrict__ bv,
                            u16* __restrict__ xb, u16* __restrict__ wqkvt,
                            u16* __restrict__ wot, float* __restrict__ bqkv) {
  const int bid = blockIdx.x;
  if (bid < 4096) {
    size_t i = ((size_t)bid * 256 + threadIdx.x) * 8;
    float4 v0 = *(const float4*)(x + i);
    float4 v1 = *(const float4*)(x + i + 4);
    uint4 o;
    o.x = pack_bf16x2(v0.x, v0.y);
    o.y = pack_bf16x2(v0.z, v0.w);
    o.z = pack_bf16x2(v1.x, v1.y);
    o.w = pack_bf16x2(v1.z, v1.w);
    *(uint4*)(xb + i) = o;
  } else if (bid < 8192) {
    __shared__ float tile[32][33];
    const int idx = bid - 4096;
    const int z = idx >> 10;
    const int rem = idx & 1023;
    const float* src = (z == 0) ? Wq : (z == 1) ? Wk : (z == 2) ? Wv : Wo;
    u16* dst = (z < 3) ? (wqkvt + (size_t)z * DMODEL * DMODEL) : wot;
    const int c0 = (rem & 31) * 32, r0 = (rem >> 5) * 32;
    const int tx = threadIdx.x & 31, ty = threadIdx.x >> 5;
#pragma unroll
    for (int i = 0; i < 4; ++i)
      tile[ty + 8 * i][tx] = src[(size_t)(r0 + ty + 8 * i) * DMODEL + c0 + tx];
    __syncthreads();
#pragma unroll
    for (int i = 0; i < 4; ++i)
      dst[(size_t)(c0 + ty + 8 * i) * DMODEL + r0 + tx] = f32_to_bf16(tile[tx][ty + 8 * i]);
  } else {
    const int i = (bid - 8192) * 256 + threadIdx.x;
    float v = (i < 1024) ? bq[i] : (i < 2048) ? bk[i - 1024] : bv[i - 2048];
    bqkv[i] = v;
  }
}

// ---------------- GEMM v5: 128x128 + TRIPLE buffer (2-deep prefetch) ----------------
// R17 post-mortem: 256x128 tile regressed (73->115us: VGPR 140 + 48KB LDS -> Occ 10.9%,
// MfmaUtil 17) - LDS-port model falsified (v3 port util was only ~42%). REVERTED to the
// 128^2 v3 skeleton. v5 change: latency depth. v3 gives a staged tile only ~1 iteration
// of flight; v5 stages 2 tiles ahead (3 LDS buffers, vmcnt(8) steady-state) -> ~2 iters
// (~4000 cyc) of flight per tile. Reuse safety: buf b read at iter t is rewritten by the
// issue at iter t+2, which is after ALL waves passed B2(t) (barrier pair unchanged).
// LDS 48KB -> 3 blocks/CU by LDS; VGPR ~76 unchanged.
template <int OUT_BF16, int FUSE_V>
__global__ __launch_bounds__(256) void gemm_bt_kernel(const u16* __restrict__ A,
                                                      const u16* __restrict__ Bt,
                                                      const float* __restrict__ bias,
                                                      void* __restrict__ Cout,
                                                      u16* __restrict__ vtout,
                                                      int M, int N, int K) {
  __shared__ u16 sA[3][128 * 32];
  __shared__ u16 sB[3][128 * 32];
  const int tid = threadIdx.x;
  const int wv = tid >> 6, lane = tid & 63;
  const int wr = wv >> 1, wc = wv & 1;
  const int col = lane & 15, quad = lane >> 4;
  const int m0 = blockIdx.x * 128;
  const int n0 = blockIdx.y * 128;

  f32x4 acc[4][4] = {};

  const int lr = tid >> 2;
  const int ls = (tid & 3) ^ ((lr >> 1) & 3); // swizzled global 16B-seg (T2 stage side)
  const size_t a_base = (size_t)(m0 + lr) * K + ls * 8;
  const size_t b_base = (size_t)(n0 + lr) * K + ls * 8;
  const int wvo = (tid >> 6) << 9; // per-wave 1KB chunk offset (u16 units)
  const int sseg = ((col >> 1) & 3); // read-side swizzle base

  // prologue: stage K-tiles 0 and 1 into buffers 0 and 1 (8 loads)
  async16(A + a_base, sA[0] + wvo);
  async16(A + a_base + (size_t)64 * K, sA[0] + wvo + 2048);
  async16(Bt + b_base, sB[0] + wvo);
  async16(Bt + b_base + (size_t)64 * K, sB[0] + wvo + 2048);
  async16(A + a_base + 32, sA[1] + wvo);
  async16(A + a_base + (size_t)64 * K + 32, sA[1] + wvo + 2048);
  async16(Bt + b_base + 32, sB[1] + wvo);
  async16(Bt + b_base + (size_t)64 * K + 32, sB[1] + wvo + 2048);

  const int nit = K >> 5;
  int cur = 0;
  for (int it = 0; it < nit; ++it) {
    // issue prefetch of K-tile it+2 into buffer (cur+2)%3, then wait for tile it's
    // 4 loads: 8 newer VMEM ops (tiles it+1, it+2) stay in flight across the barriers.
    if (it + 2 < nit) {
      const int pb = (cur == 0) ? 2 : cur - 1; // (cur+2)%3
      const int k0 = (it + 2) << 5;
      async16(A + a_base + k0, sA[pb] + wvo);
      async16(A + a_base + (size_t)64 * K + k0, sA[pb] + wvo + 2048);
      async16(Bt + b_base + k0, sB[pb] + wvo);
      async16(Bt + b_base + (size_t)64 * K + k0, sB[pb] + wvo + 2048);
      asm volatile("s_waitcnt vmcnt(8)");
    } else if (it + 1 < nit) {
      asm volatile("s_waitcnt vmcnt(4)");
    } else {
      asm volatile("s_waitcnt vmcnt(0)");
    }
    __builtin_amdgcn_sched_barrier(0);
    __builtin_amdgcn_s_barrier(); // B1: K-tile it staged by ALL waves
    __builtin_amdgcn_sched_barrier(0);

    const int rseg = (quad ^ sseg) * 8;
    bf16x8 af[4], bfr[4];
#pragma unroll
    for (int i = 0; i < 4; ++i)
      af[i] = *(const bf16x8*)(sA[cur] + (wr * 64 + i * 16 + col) * 32 + rseg);
#pragma unroll
    for (int j = 0; j < 4; ++j)
      bfr[j] = *(const bf16x8*)(sB[cur] + (wc * 64 + j * 16 + col) * 32 + rseg);
#pragma unroll
    for (int i = 0; i < 4; ++i)
#pragma unroll
      for (int j = 0; j < 4; ++j)
        acc[i][j] = __builtin_amdgcn_mfma_f32_16x16x32_bf16(af[i], bfr[j], acc[i][j], 0, 0, 0);

    __builtin_amdgcn_sched_barrier(0);
    __builtin_amdgcn_s_barrier(); // B2: all waves done reading cur (no vmcnt drain)
    __builtin_amdgcn_sched_barrier(0);
    cur = (cur == 2) ? 0 : cur + 1;
  }

#pragma unroll
  for (int i = 0; i < 4; ++i) {
#pragma unroll
    for (int j = 0; j < 4; ++j) {
      int n = n0 + wc * 64 + j * 16 + col;
      float bia = bias[n];
      if (FUSE_V && n >= 2 * DMODEL) {
        // V column -> vt[((b*16+h)*64+dh)][s], 4 consecutive s packed into one 8B store
        const int hh = (n - 2 * DMODEL) >> 6, dh = n & 63;
        const int mb = m0 + wr * 64 + i * 16 + quad * 4;
        const int bb = mb >> 11, s0 = mb & 2047;
        uint2 pk;
        pk.x = pack_bf16x2(acc[i][j][0] + bia, acc[i][j][1] + bia);
        pk.y = pack_bf16x2(acc[i][j][2] + bia, acc[i][j][3] + bia);
        *(uint2*)(vtout + ((size_t)((bb * 16 + hh) * 64 + dh)) * SLEN + s0) = pk;
      } else {
        const int cstride = FUSE_V ? (2 * DMODEL) : N;
#pragma unroll
        for (int r = 0; r < 4; ++r) {
          int m = m0 + wr * 64 + i * 16 + quad * 4 + r;
          float v = acc[i][j][r] + bia;
          if (OUT_BF16)
            ((u16*)Cout)[(size_t)m * cstride + n] = f32_to_bf16(v);
          else
            ((float*)Cout)[(size_t)m * cstride + n] = v;
        }
      }
    }
  }
}

// ---------------- flash attention v18: grid (16,64), no register cap (R14 best, unchanged) ----------------
__global__ __launch_bounds__(256, 2) void attn_kernel(const u16* __restrict__ qk,
                                                      const u16* __restrict__ vt,
                                                      u16* __restrict__ out) {
  const int lid = blockIdx.y * 16 + blockIdx.x; // [0,1024)
  const int xcd = lid & 7;
  const int local = lid >> 3;            // [0,128)
  const int bh = xcd * 8 + (local & 7);  // same-bh blocks share XCD
  const int bx = 15 - (local >> 3);      // 0..15, heavy blocks (large bx) launch early
  const int b = bh >> 4, h = bh & 15;
  const int tid = threadIdx.x;
  const int wv = tid >> 6, lane = tid & 63;
  const int c = lane & 31, hi = lane >> 5;
  const int s = bx * 4 + wv; // strip id 0..63 (32 q-rows each)

  __shared__ u16 sK[2][64 * 64];
  __shared__ u16 sV[2][64 * 64];

  const u16* kbase = qk + ((size_t)(b * SLEN)) * (2 * DMODEL) + DMODEL + h * DHEAD;
  const u16* vbase = vt + ((size_t)bh * DHEAD) * SLEN;
  const float scl2 = 0.125f * 1.44269504088896f; // 1/sqrt(dh) * log2(e)

  const int lrow = lane >> 3;
  const int sga = (lane & 7) ^ lrow;
  const int r0a = wv * 16, r0b = wv * 16 + 8;
  const int cs = c & 7;

  const int qbase = s * 32;
  const int nt_own = s / 2 + 1;
  const int nt = 2 * bx + 2; // block-uniform staging sweep (= max nt_own in block)

  const u16* qrow =
      qk + ((size_t)(b * SLEN + qbase + c)) * (2 * DMODEL) + h * DHEAD + hi * 8;
  bf16x8 aQ[4];
#pragma unroll
  for (int ks = 0; ks < 4; ++ks) aQ[ks] = *(const bf16x8*)(qrow + ks * 16);

  f32x16 accO[2] = {}; // [mdh]: O^T, col=q=c, row=dh=mdh*32+(r&3)+8*(r>>2)+4*hi
  float m2 = -1e30f, l_i = 0.0f;

  async16(kbase + (size_t)(r0a + lrow) * (2 * DMODEL) + sga * 8, sK[0] + r0a * 64);
  async16(kbase + (size_t)(r0b + lrow) * (2 * DMODEL) + sga * 8, sK[0] + r0b * 64);
  async16(vbase + (size_t)(r0a + lrow) * SLEN + sga * 8, sV[0] + r0a * 64);
  async16(vbase + (size_t)(r0b + lrow) * SLEN + sga * 8, sV[0] + r0b * 64);

  for (int t = 0; t < nt; ++t) {
    const int kv0 = t * 64;
    const int cur = t & 1, nxt = cur ^ 1;

    if (t + 1 < nt) {
      const int kvn = kv0 + 64;
      async16(kbase + (size_t)(kvn + r0a + lrow) * (2 * DMODEL) + sga * 8, sK[nxt] + r0a * 64);
      async16(kbase + (size_t)(kvn + r0b + lrow) * (2 * DMODEL) + sga * 8, sK[nxt] + r0b * 64);
      async16(vbase + (size_t)(r0a + lrow) * SLEN + kvn + sga * 8, sV[nxt] + r0a * 64);
      async16(vbase + (size_t)(r0b + lrow) * SLEN + kvn + sga * 8, sV[nxt] + r0b * 64);
      asm volatile("s_waitcnt vmcnt(4)");
    } else {
      asm volatile("s_waitcnt vmcnt(0)");
    }
    __builtin_amdgcn_sched_barrier(0);
    __builtin_amdgcn_s_barrier(); // B1: tile t staged by ALL waves
    __builtin_amdgcn_sched_barrier(0);

    if (t < nt_own) {
      const u16* sKc = sK[cur];
      const u16* sVc = sV[cur];
      bf16x8 bK[2][4], bV[2][4];
#pragma unroll
      for (int m = 0; m < 2; ++m) {
        const int rb = (m * 32 + c) * 64;
#pragma unroll
        for (int ks = 0; ks < 4; ++ks) {
          bK[m][ks] = *(const bf16x8*)(sKc + rb + (((ks * 2 + hi) ^ cs) << 3));
          bf16x4 vlo = *(const bf16x4*)(sVc + rb + (((ks * 2) ^ cs) << 3) + 4 * hi);
          bf16x4 vhi = *(const bf16x4*)(sVc + rb + (((ks * 2 + 1) ^ cs) << 3) + 4 * hi);
          bV[m][ks] = __builtin_shufflevector(vlo, vhi, 0, 1, 2, 3, 4, 5, 6, 7);
        }
      }

      f32x16 accST[2] = {};
      __builtin_amdgcn_s_setprio(1);
#pragma unroll
      for (int ks = 0; ks < 4; ++ks)
#pragma unroll
        for (int m = 0; m < 2; ++m)
          accST[m] = __builtin_amdgcn_mfma_f32_32x32x16_bf16(bK[m][ks], aQ[ks],
                                                             accST[m], 0, 0, 0);
      __builtin_amdgcn_s_setprio(0);

      if (t == nt_own - 1) {
        const int q = qbase + c;
        const int kvh = kv0 + 4 * hi;
#pragma unroll
        for (int m = 0; m < 2; ++m)
#pragma unroll
          for (int r = 0; r < 16; ++r) {
            int kv = kvh + m * 32 + ((r & 3) + 8 * (r >> 2));
            if (kv > q) accST[m][r] = -1e30f;
          }
      }

      float h0 = fmaxf(fmaxf(accST[0][0], accST[0][1]), fmaxf(accST[0][2], accST[0][3]));
      float h1 = fmaxf(fmaxf(accST[0][4], accST[0][5]), fmaxf(accST[0][6], accST[0][7]));
      float h2 = fmaxf(fmaxf(accST[0][8], accST[0][9]), fmaxf(accST[0][10], accST[0][11]));
      float h3 = fmaxf(fmaxf(accST[0][12], accST[0][13]), fmaxf(accST[0][14], accST[0][15]));
      float h4 = fmaxf(fmaxf(accST[1][0], accST[1][1]), fmaxf(accST[1][2], accST[1][3]));
      float h5 = fmaxf(fmaxf(accST[1][4], accST[1][5]), fmaxf(accST[1][6], accST[1][7]));
      float h6 = fmaxf(fmaxf(accST[1][8], accST[1][9]), fmaxf(accST[1][10], accST[1][11]));
      float h7 = fmaxf(fmaxf(accST[1][12], accST[1][13]), fmaxf(accST[1][14], accST[1][15]));
      float rmax = fmaxf(fmaxf(fmaxf(h0, h1), fmaxf(h2, h3)),
                         fmaxf(fmaxf(h4, h5), fmaxf(h6, h7)));
      rmax = fmaxf(rmax, __shfl_xor(rmax, 32));
      float rmaxs = rmax * scl2;
      const bool noresc = __all(rmaxs <= m2);
      float mnew = noresc ? m2 : fmaxf(m2, rmaxs);
      float alpha = noresc ? 1.0f : EXP2(m2 - mnew);
      m2 = mnew;

      float s0 = 0.f, s1 = 0.f, s2s = 0.f, s3 = 0.f;
#pragma unroll
      for (int m = 0; m < 2; ++m) {
#pragma unroll
        for (int r = 0; r < 16; r += 4) {
          float p0 = EXP2(__builtin_fmaf(accST[m][r + 0], scl2, -mnew));
          float p1 = EXP2(__builtin_fmaf(accST[m][r + 1], scl2, -mnew));
          float p2 = EXP2(__builtin_fmaf(accST[m][r + 2], scl2, -mnew));
          float p3 = EXP2(__builtin_fmaf(accST[m][r + 3], scl2, -mnew));
          accST[m][r + 0] = p0;
          accST[m][r + 1] = p1;
          accST[m][r + 2] = p2;
          accST[m][r + 3] = p3;
          s0 += p0;
          s1 += p1;
          s2s += p2;
          s3 += p3;
        }
      }
      float sacc = (s0 + s1) + (s2s + s3);
      sacc += __shfl_xor(sacc, 32);
      if (noresc) {
        l_i += sacc;
      } else {
        l_i = l_i * alpha + sacc;
#pragma unroll
        for (int m = 0; m < 2; ++m)
#pragma unroll
          for (int r = 0; r < 16; ++r) accO[m][r] *= alpha;
      }

      bf16x8 aP[4];
#pragma unroll
      for (int m = 0; m < 2; ++m)
#pragma unroll
        for (int sp = 0; sp < 2; ++sp) {
          union {
            uint4 u;
            bf16x8 v;
          } cvt;
          cvt.u.x = pack_trunc(accST[m][8 * sp + 0], accST[m][8 * sp + 1]);
          cvt.u.y = pack_trunc(accST[m][8 * sp + 2], accST[m][8 * sp + 3]);
          cvt.u.z = pack_trunc(accST[m][8 * sp + 4], accST[m][8 * sp + 5]);
          cvt.u.w = pack_trunc(accST[m][8 * sp + 6], accST[m][8 * sp + 7]);
          aP[m * 2 + sp] = cvt.v;
        }

      __builtin_amdgcn_s_setprio(1);
#pragma unroll
      for (int ks = 0; ks < 4; ++ks)
#pragma unroll
        for (int m = 0; m < 2; ++m)
          accO[m] = __builtin_amdgcn_mfma_f32_32x32x16_bf16(bV[m][ks], aP[ks],
                                                            accO[m], 0, 0, 0);
      __builtin_amdgcn_s_setprio(0);
    }

    __builtin_amdgcn_sched_barrier(0);
    __builtin_amdgcn_s_barrier(); // B2: all waves done reading cur (no vmcnt drain)
    __builtin_amdgcn_sched_barrier(0);
  }

  {
    float rl = 1.0f / l_i;
    size_t rowoff =
        ((size_t)(b * SLEN + qbase + c)) * DMODEL + h * DHEAD + 4 * hi;
#pragma unroll
    for (int m = 0; m < 2; ++m)
#pragma unroll
      for (int j = 0; j < 4; ++j) {
        uint2 pk;
        pk.x = pack_round(accO[m][4 * j + 0] * rl, accO[m][4 * j + 1] * rl);
        pk.y = pack_round(accO[m][4 * j + 2] * rl, accO[m][4 * j + 3] * rl);
        *(uint2*)(out + rowoff + m * 32 + 8 * j) = pk;
      }
  }
}

// ---------------- launch ----------------

extern "C" void kernel_launch(void* const* d_in, const int* in_sizes, int n_in,
                              void* d_out, int out_size, void* d_ws, size_t ws_size,
                              hipStream_t stream) {
  const float* x = (const float*)d_in[0];
  const float* Wq = (const float*)d_in[1];
  const float* bq = (const float*)d_in[2];
  const float* Wk = (const float*)d_in[3];
  const float* bk = (const float*)d_in[4];
  const float* Wv = (const float*)d_in[5];
  const float* bv = (const float*)d_in[6];
  const float* Wo = (const float*)d_in[7];
  const float* bo = (const float*)d_in[8];

  char* ws = (char*)d_ws;
  u16* xb = (u16*)ws;                              // 16 MB
  u16* wqkvt = (u16*)(ws + ((size_t)16 << 20));    // 6 MB
  u16* wot = (u16*)(ws + ((size_t)22 << 20));      // 2 MB
  u16* qk = (u16*)(ws + ((size_t)24 << 20));       // 32 MB (Q|K, row stride 2048)
  u16* vtp = (u16*)(ws + ((size_t)56 << 20));      // 16 MB (V transposed, fused write)
  u16* attnO = (u16*)(ws + ((size_t)72 << 20));    // 16 MB
  float* bqkv = (float*)(ws + ((size_t)88 << 20)); // 12 KB

  prep_kernel<<<8204, 256, 0, stream>>>(x, Wq, Wk, Wv, Wo, bq, bk, bv,
                                        xb, wqkvt, wot, bqkv);
  gemm_bt_kernel<1, 1><<<dim3(64, 24), 256, 0, stream>>>(xb, wqkvt, bqkv, (void*)qk, vtp,
                                                         MROWS, 3 * DMODEL, DMODEL);
  attn_kernel<<<dim3(16, 64), 256, 0, stream>>>(qk, vtp, attnO);
  gemm_bt_kernel<0, 0><<<dim3(64, 8), 256, 0, stream>>>(attnO, wot, bo, d_out, nullptr,
                                                        MROWS, DMODEL, DMODEL);
}